// Round 1
// baseline (351.918 us; speedup 1.0000x reference)
//
#include <hip/hip_runtime.h>
#include <math.h>

#define B_     2
#define L_     768
#define SIN_   1280
#define SOUT_  32
#define DI_    64
#define DST_   16
#define DCONV_ 4
#define DTR_   2
#define NCH    48
#define CH     16

// ---------------- workspace layout (float offsets) ----------------
// gate : [B*L][64]        off 0
// xs   : [B*L][64]        off 98304
// dtf  : [B*L][64]        off 196608
// dtx  : [B*L][64]        off 294912
// Bws  : [B*L][16]        off 393216
// Cws  : [B*L][16]        off 417792
// Pst  : [B*NCH][64][16]  off 442368
// Lst  : [B*NCH][64][16]  off 540672
// Hst  : [B*NCH][64][16]  off 638976
// total 737280 floats = 2.95 MB (< previous 3.74 MB)

// K1: fused front end. One block per (batch, 16-row chunk).
// s_proj (with 3-row conv halo) -> in_proj -> conv+SiLU -> x_proj ->
// dt/softplus -> local chunk scan (old p1). All intermediates in LDS.
__global__ __launch_bounds__(256) void k_front(
    const float* __restrict__ s, const float* __restrict__ spw,
    const float* __restrict__ spb, const float* __restrict__ ipw,
    const float* __restrict__ convw, const float* __restrict__ convb,
    const float* __restrict__ xpw, const float* __restrict__ dtw,
    const float* __restrict__ dtb, const float* __restrict__ Alog,
    float* __restrict__ gate_o, float* __restrict__ xs_o,
    float* __restrict__ dtf_o, float* __restrict__ dtx_o,
    float* __restrict__ Bws, float* __restrict__ Cws,
    float* __restrict__ Pst, float* __restrict__ Lst)
{
    const int bc  = blockIdx.x;               // b*NCH + c
    const int b   = bc / NCH, c = bc - b * NCH;
    const int l0  = c * CH;                   // first own row in batch
    const int tid = threadIdx.x;

    __shared__ float sw2[128 * 33];           // in_proj_w, stride 33 (bank-conflict-free)
    __shared__ float sxpw[64][34];            // x_proj_w transposed
    __shared__ float sdtw[128];
    __shared__ float srow[4][SIN_];           // 4 staged s rows
    __shared__ float su[20][SOUT_];           // s_proj out, rows l0-3 .. l0+16
    __shared__ float sx[20][DI_];             // conv input (in_proj x-half)
    __shared__ float sxs[CH][DI_];            // silu(conv) for own rows
    __shared__ float sxd[CH][34];             // x_proj out
    __shared__ float sdtf[CH][DI_];
    __shared__ float sdtx[CH][DI_];
    __shared__ float sB[CH][DST_];

    // stage weights (padded / transposed)
    for (int i = tid; i < 128 * 32; i += 256)
        sw2[(i >> 5) * 33 + (i & 31)] = ipw[i];
    for (int i = tid; i < 34 * 64; i += 256)
        sxpw[i & 63][i >> 6] = xpw[i];
    if (tid < 128) sdtw[tid] = dtw[tid];

    // ---- s_proj for rows l0-3 .. l0+16 (20 slots, 5 groups of 4) ----
    const int f  = tid >> 3;                  // 0..31 output feature
    const int cc = tid & 7;                   // 0..7  k-slice
    for (int g = 0; g < 5; ++g) {
        for (int rr = 0; rr < 4; ++rr) {
            int l = l0 - 3 + g * 4 + rr;
            if (l >= 0 && l < L_) {
                const float* src = s + ((long)(b * L_ + l)) * SIN_;
                for (int i = tid; i < SIN_; i += 256) srow[rr][i] = src[i];
            } else {
                for (int i = tid; i < SIN_; i += 256) srow[rr][i] = 0.f;
            }
        }
        __syncthreads();
        float p0 = 0.f, p1 = 0.f, p2 = 0.f, p3 = 0.f;
        const float* wrow = spw + (long)f * SIN_;
        for (int k = cc; k < SIN_; k += 8) {
            float w = wrow[k];
            p0 += srow[0][k] * w; p1 += srow[1][k] * w;
            p2 += srow[2][k] * w; p3 += srow[3][k] * w;
        }
        #pragma unroll
        for (int m = 1; m <= 4; m <<= 1) {
            p0 += __shfl_xor(p0, m); p1 += __shfl_xor(p1, m);
            p2 += __shfl_xor(p2, m); p3 += __shfl_xor(p3, m);
        }
        if (cc == 0) {
            float bb = spb[f];
            #pragma unroll
            for (int rr = 0; rr < 4; ++rr) {
                int l = l0 - 3 + g * 4 + rr;
                float pv = (rr == 0) ? p0 : (rr == 1) ? p1 : (rr == 2) ? p2 : p3;
                su[g * 4 + rr][f] = (l >= 0 && l < L_) ? pv + bb : 0.f;
            }
        }
        __syncthreads();
    }

    // ---- in_proj: x-half for the 19 halo+own rows, gate for own rows ----
    for (int i = tid; i < 19 * 64; i += 256) {
        int si = i >> 6, j = i & 63;
        const float* w = &sw2[j * 33];
        float acc = 0.f;
        #pragma unroll
        for (int k = 0; k < SOUT_; ++k) acc += su[si][k] * w[k];
        sx[si][j] = acc;
    }
    for (int i = tid; i < CH * 64; i += 256) {
        int r = i >> 6, j = i & 63;
        const float* w = &sw2[(64 + j) * 33];
        float acc = 0.f;
        #pragma unroll
        for (int k = 0; k < SOUT_; ++k) acc += su[r + 3][k] * w[k];
        gate_o[((long)(b * L_ + l0 + r)) * DI_ + j] = acc;
    }
    __syncthreads();

    // ---- causal conv (kernel 4) + SiLU ----
    for (int i = tid; i < CH * DI_; i += 256) {
        int r = i >> 6, d = i & 63;
        float xc = convb[d];
        #pragma unroll
        for (int k = 0; k < DCONV_; ++k)
            xc = fmaf(sx[r + k][d], convw[d * 4 + k], xc);   // row l0+r-3+k -> slot r+k
        float xv = xc / (1.f + expf(-xc));
        sxs[r][d] = xv;
        xs_o[((long)(b * L_ + l0 + r)) * DI_ + d] = xv;
    }
    __syncthreads();

    // ---- x_proj: [16][64] @ [64][34] ----
    for (int i = tid; i < CH * 34; i += 256) {
        int r = i / 34, o = i - r * 34;
        float acc = 0.f;
        #pragma unroll
        for (int k = 0; k < DI_; ++k) acc = fmaf(sxs[r][k], sxpw[k][o], acc);
        sxd[r][o] = acc;
    }
    __syncthreads();

    // ---- dt path + B/C extraction ----
    for (int i = tid; i < CH * DI_; i += 256) {
        int r = i >> 6, d = i & 63;
        float dtv = fmaf(sxd[r][0], sdtw[2 * d], fmaf(sxd[r][1], sdtw[2 * d + 1], dtb[d]));
        dtv = dtv > 20.f ? dtv : log1pf(expf(dtv));           // softplus
        float xv = sxs[r][d];
        sdtf[r][d] = dtv;
        sdtx[r][d] = dtv * xv;
        long o = ((long)(b * L_ + l0 + r)) * DI_ + d;
        dtf_o[o] = dtv;
        dtx_o[o] = dtv * xv;
    }
    {
        int r = tid >> 4, n = tid & 15;                        // 16x16 = 256 exactly
        float Bv = sxd[r][DTR_ + n];
        float Cv = sxd[r][DTR_ + DST_ + n];
        sB[r][n] = Bv;
        long o = ((long)(b * L_ + l0 + r)) * DST_ + n;
        Bws[o] = Bv;
        Cws[o] = Cv;
    }
    __syncthreads();

    // ---- local chunk scan (old p1): thread d owns h[16] in regs ----
    if (tid < 64) {
        const int d = tid;
        float A2[DST_], P[DST_], hl[DST_];
        #pragma unroll
        for (int n = 0; n < DST_; ++n) {
            A2[n] = -expf(Alog[d * DST_ + n]) * 1.44269504088896f;
            P[n] = 1.f; hl[n] = 0.f;
        }
        #pragma unroll
        for (int l = 0; l < CH; ++l) {
            float dt = sdtf[l][d];
            float dx = sdtx[l][d];
            #pragma unroll
            for (int n = 0; n < DST_; ++n) {
                float a = exp2f(dt * A2[n]);
                P[n] *= a;
                hl[n] = fmaf(a, hl[n], dx * sB[l][n]);
            }
        }
        float4* Pp = (float4*)(Pst + ((long)bc * 64 + d) * 16);
        float4* Lp = (float4*)(Lst + ((long)bc * 64 + d) * 16);
        #pragma unroll
        for (int q = 0; q < 4; ++q) {
            Pp[q] = ((float4*)P)[q];
            Lp[q] = ((float4*)hl)[q];
        }
    }
}

// K2: carry combine over chunks. 2048 independent (b,d,n) chains, 48 steps.
__global__ __launch_bounds__(256) void k_carry(
    const float* __restrict__ Pst, const float* __restrict__ Lst,
    float* __restrict__ Hst)
{
    const int idx = blockIdx.x * 256 + threadIdx.x;   // 0..2047
    const int b = idx >> 10, e = idx & 1023;
    float H = 0.f;
    #pragma unroll 8
    for (int c = 0; c < NCH; ++c) {
        long o = ((long)(b * NCH + c)) * 1024 + e;
        Hst[o] = H;
        H = fmaf(Pst[o], H, Lst[o]);
    }
}

// K3: fused back end. Chunk re-scan from true start state (old p3) +
// D-skip + gated SiLU + out_proj epilogue (old k_epi).
__global__ __launch_bounds__(256) void k_back(
    const float* __restrict__ dtf, const float* __restrict__ dtx,
    const float* __restrict__ Bws, const float* __restrict__ Cws,
    const float* __restrict__ Alog, const float* __restrict__ Hst,
    const float* __restrict__ xs, const float* __restrict__ gate,
    const float* __restrict__ Dv, const float* __restrict__ opw,
    float* __restrict__ sp)
{
    const int bc  = blockIdx.x;
    const int b   = bc / NCH, c = bc - b * NCH;
    const int l0  = c * CH;
    const int tid = threadIdx.x;
    const long rbase = (long)(b * L_ + l0);

    __shared__ float sB[CH][DST_], sC[CH][DST_];
    __shared__ float sdtf[CH][DI_], sdtx[CH][DI_];
    __shared__ float sy[CH][DI_];
    __shared__ float sw[DI_][SOUT_];          // out_proj_w transposed

    for (int i = tid; i < CH * DST_; i += 256) {
        sB[i >> 4][i & 15] = Bws[rbase * DST_ + i];
        sC[i >> 4][i & 15] = Cws[rbase * DST_ + i];
    }
    for (int i = tid; i < CH * DI_; i += 256) {
        sdtf[i >> 6][i & 63] = dtf[rbase * DI_ + i];
        sdtx[i >> 6][i & 63] = dtx[rbase * DI_ + i];
    }
    for (int i = tid; i < SOUT_ * DI_; i += 256)
        sw[i & 63][i >> 6] = opw[i];
    __syncthreads();

    if (tid < 64) {
        const int d = tid;
        float A2[DST_], h[DST_];
        #pragma unroll
        for (int n = 0; n < DST_; ++n)
            A2[n] = -expf(Alog[d * DST_ + n]) * 1.44269504088896f;
        const float4* Hp = (const float4*)(Hst + ((long)bc * 64 + d) * 16);
        #pragma unroll
        for (int q = 0; q < 4; ++q) ((float4*)h)[q] = Hp[q];
        #pragma unroll
        for (int l = 0; l < CH; ++l) {
            float dt = sdtf[l][d];
            float dx = sdtx[l][d];
            float y = 0.f;
            #pragma unroll
            for (int n = 0; n < DST_; ++n) {
                float a = exp2f(dt * A2[n]);
                h[n] = fmaf(a, h[n], dx * sB[l][n]);
                y = fmaf(h[n], sC[l][n], y);
            }
            sy[l][d] = y;
        }
    }
    __syncthreads();

    // yv = (y + xs*D) * silu(gate)
    for (int i = tid; i < CH * DI_; i += 256) {
        int r = i >> 6, d = i & 63;
        float g  = gate[(rbase + r) * DI_ + d];
        float yv = fmaf(xs[(rbase + r) * DI_ + d], Dv[d], sy[r][d]);
        sy[r][d] = yv * (g / (1.f + expf(-g)));
    }
    __syncthreads();

    // sp = yv @ out_proj_w.T : 16 rows x 32 outs, 64-dot each
    for (int i = tid; i < CH * SOUT_; i += 256) {
        int r = i >> 5, o = i & 31;
        float acc = 0.f;
        #pragma unroll
        for (int k = 0; k < DI_; ++k) acc = fmaf(sy[r][k], sw[k][o], acc);
        sp[(rbase + r) * SOUT_ + o] = acc;
    }
}

// K4: z_prime[b,s,t,f] = z[b,s,t]*zw[f] + zb[f] + sp[b,s,f]*sp[b,t,f]
__global__ __launch_bounds__(256) void k_z(
    const float* __restrict__ z, const float* __restrict__ zw,
    const float* __restrict__ zb, const float* __restrict__ sp,
    float* __restrict__ zout)
{
    const int idx = blockIdx.x * 256 + threadIdx.x;   // < B*L*L*8 = 9437184
    const int bs  = idx / 6144;         // b*L + s   (6144 = L*8 float4s)
    const int rem = idx - bs * 6144;
    const int t   = rem >> 3;
    const int f4  = rem & 7;
    const int b   = bs / L_;

    float zval = z[(long)bs * L_ + t];
    float4 w4 = ((const float4*)zw)[f4];
    float4 b4 = ((const float4*)zb)[f4];
    float4 ss = ((const float4*)sp)[bs * 8 + f4];
    float4 st = ((const float4*)sp)[(b * L_ + t) * 8 + f4];
    float4 o;
    o.x = zval * w4.x + b4.x + ss.x * st.x;
    o.y = zval * w4.y + b4.y + ss.y * st.y;
    o.z = zval * w4.z + b4.z + ss.z * st.z;
    o.w = zval * w4.w + b4.w + ss.w * st.w;
    ((float4*)zout)[(long)idx] = o;
}

extern "C" void kernel_launch(void* const* d_in, const int* in_sizes, int n_in,
                              void* d_out, int out_size, void* d_ws, size_t ws_size,
                              hipStream_t stream) {
    const float* s     = (const float*)d_in[0];
    const float* z     = (const float*)d_in[1];
    const float* spw   = (const float*)d_in[2];
    const float* spb   = (const float*)d_in[3];
    const float* zw    = (const float*)d_in[4];
    const float* zb    = (const float*)d_in[5];
    const float* ipw   = (const float*)d_in[6];
    const float* convw = (const float*)d_in[7];
    const float* convb = (const float*)d_in[8];
    const float* xpw   = (const float*)d_in[9];
    const float* dtw   = (const float*)d_in[10];
    const float* dtb   = (const float*)d_in[11];
    const float* Alog  = (const float*)d_in[12];
    const float* Dv    = (const float*)d_in[13];
    const float* opw   = (const float*)d_in[14];

    float* out  = (float*)d_out;
    float* ws   = (float*)d_ws;
    float* gate = ws;
    float* xs   = ws + 98304;
    float* dtf  = ws + 196608;
    float* dtx  = ws + 294912;
    float* Bws  = ws + 393216;
    float* Cws  = ws + 417792;
    float* Pst  = ws + 442368;
    float* Lst  = ws + 540672;
    float* Hst  = ws + 638976;

    float* sp   = out;            // s_prime: first 49152 floats of d_out
    float* zout = out + 49152;    // z_prime: remaining 37748736 floats

    k_front<<<B_ * NCH, 256, 0, stream>>>(s, spw, spb, ipw, convw, convb, xpw,
                                          dtw, dtb, Alog, gate, xs, dtf, dtx,
                                          Bws, Cws, Pst, Lst);
    k_carry<<<8, 256, 0, stream>>>(Pst, Lst, Hst);
    k_back <<<B_ * NCH, 256, 0, stream>>>(dtf, dtx, Bws, Cws, Alog, Hst,
                                          xs, gate, Dv, opw, sp);
    k_z    <<<(B_ * L_ * L_ * 8) / 256, 256, 0, stream>>>(z, zw, zb, sp, zout);
}

// Round 2
// 260.842 us; speedup vs baseline: 1.3492x; 1.3492x over previous
//
#include <hip/hip_runtime.h>
#include <math.h>

#define B_     2
#define L_     768
#define SIN_   1280
#define SOUT_  32
#define DI_    64
#define DST_   16
#define DCONV_ 4
#define DTR_   2
#define NCH    48
#define CH     16

// ---------------- workspace layout (float offsets) ----------------
// xz   : [B*L][128]       off 0       (x = [:,0:64], gate = [:,64:128])
// xs   : [B*L][64]        off 196608
// dtf  : [B*L][64]        off 294912
// dtx  : [B*L][64]        off 393216
// Bws  : [B*L][16]        off 491520
// Cws  : [B*L][16]        off 516096
// Pst  : [B*NCH][64][16]  off 540672
// Lst  : [B*NCH][64][16]  off 638976
// Hst  : [B*NCH][64][16]  off 737280
// total 835584 floats = 3.34 MB

// K1: s_prime_pre = s @ s_proj_w.T + b, then xz = u @ in_proj_w.T
// 384 blocks x 256. w2 padded to stride 33 -> conflict-free phase 2.
__global__ __launch_bounds__(256) void k_sproj(
    const float* __restrict__ s, const float* __restrict__ spw,
    const float* __restrict__ spb, const float* __restrict__ ipw,
    float* __restrict__ xz)
{
    __shared__ float srow[4][SIN_];
    __shared__ float w2[128 * 33];          // in_proj_w, stride 33
    __shared__ float u[4][SOUT_];
    const int tid = threadIdx.x;
    const int row0 = blockIdx.x * 4;

    for (int r = 0; r < 4; ++r) {
        const float4* src = (const float4*)(s + (long)(row0 + r) * SIN_);
        for (int i = tid; i < SIN_ / 4; i += 256)
            ((float4*)srow[r])[i] = src[i];
    }
    for (int i = tid; i < 128 * 32; i += 256)
        w2[(i >> 5) * 33 + (i & 31)] = ipw[i];
    __syncthreads();

    const int f = tid >> 3;      // 0..31
    const int c = tid & 7;       // 0..7
    float p0 = 0.f, p1 = 0.f, p2 = 0.f, p3 = 0.f;
    const float* wrow = spw + (long)f * SIN_;
    for (int k = c; k < SIN_; k += 8) {
        float w = wrow[k];
        p0 += srow[0][k] * w; p1 += srow[1][k] * w;
        p2 += srow[2][k] * w; p3 += srow[3][k] * w;
    }
    #pragma unroll
    for (int m = 1; m <= 4; m <<= 1) {
        p0 += __shfl_xor(p0, m); p1 += __shfl_xor(p1, m);
        p2 += __shfl_xor(p2, m); p3 += __shfl_xor(p3, m);
    }
    if (c == 0) {
        float b = spb[f];
        u[0][f] = p0 + b; u[1][f] = p1 + b;
        u[2][f] = p2 + b; u[3][f] = p3 + b;
    }
    __syncthreads();

    const int j  = tid & 127;    // output channel of xz
    const int rh = tid >> 7;     // 0..1
    #pragma unroll
    for (int rp = 0; rp < 2; ++rp) {
        int r = rp * 2 + rh;
        float acc = 0.f;
        const float* wj = &w2[j * 33];
        #pragma unroll
        for (int k = 0; k < SOUT_; ++k) acc += u[r][k] * wj[k];
        xz[(long)(row0 + r) * 128 + j] = acc;
    }
}

// K2: conv + SiLU + x_proj + dt path. 4 rows per 256-thread block.
__global__ __launch_bounds__(256) void k_pre(
    const float* __restrict__ xz, const float* __restrict__ convw,
    const float* __restrict__ convb, const float* __restrict__ xpw,
    const float* __restrict__ dtw, const float* __restrict__ dtb,
    float* __restrict__ xs_out, float* __restrict__ dtf,
    float* __restrict__ dtx, float* __restrict__ Bws, float* __restrict__ Cws)
{
    const int row0 = blockIdx.x * 4;
    const int tid = threadIdx.x;
    const int r = tid >> 6, d = tid & 63;
    const int row = row0 + r;                  // block never crosses batch
    const int b = row / L_, l = row - b * L_;
    __shared__ float sxpw[64][34];             // x_proj_w transposed
    __shared__ float sdtw[128];
    __shared__ float sxs[4][DI_];
    __shared__ float sxd[4][34];

    for (int i = tid; i < 34 * 64; i += 256) {
        int j = i >> 6, k = i & 63;
        sxpw[k][j] = xpw[i];
    }
    if (tid < 128) sdtw[tid] = dtw[tid];

    float xc = convb[d];
    #pragma unroll
    for (int k = 0; k < DCONV_; ++k) {
        int ls = l + k - (DCONV_ - 1);
        if (ls >= 0) xc = fmaf(xz[(long)(b * L_ + ls) * 128 + d], convw[d * 4 + k], xc);
    }
    float xsv = xc / (1.f + expf(-xc));        // SiLU
    sxs[r][d] = xsv;
    xs_out[(long)row * DI_ + d] = xsv;
    __syncthreads();

    if (d < DTR_ + 2 * DST_) {
        float acc = 0.f;
        #pragma unroll
        for (int k = 0; k < 64; ++k) acc = fmaf(sxs[r][k], sxpw[k][d], acc);
        sxd[r][d] = acc;
    }
    __syncthreads();

    if (d < DST_) {
        Bws[(long)row * DST_ + d] = sxd[r][DTR_ + d];
        Cws[(long)row * DST_ + d] = sxd[r][DTR_ + DST_ + d];
    }
    float dtv = fmaf(sxd[r][0], sdtw[d * 2], fmaf(sxd[r][1], sdtw[d * 2 + 1], dtb[d]));
    dtv = dtv > 20.f ? dtv : log1pf(expf(dtv));   // softplus
    dtf[(long)row * DI_ + d] = dtv;
    dtx[(long)row * DI_ + d] = dtv * xsv;
}

// K3: local chunk scan, (d,n) decomposition. 384 blocks x 256 threads.
// block = (b, chunk, dq); thread = (dl, n); per-thread state: P, hl (2 regs).
__global__ __launch_bounds__(256) void k_scan_p1(
    const float* __restrict__ dtf, const float* __restrict__ dtx,
    const float* __restrict__ Bws, const float* __restrict__ Alog,
    float* __restrict__ Pst, float* __restrict__ Lst)
{
    const int blk = blockIdx.x;                // bc*4 + dq
    const int dq  = blk & 3;
    const int bc  = blk >> 2;                  // b*NCH + c
    const int b   = bc / NCH, c = bc - b * NCH;
    const int tid = threadIdx.x;
    const int dl  = tid >> 4, n = tid & 15;
    const int d   = dq * 16 + dl;
    const long base = (long)b * L_ + c * CH;

    __shared__ float sB[CH][16];
    __shared__ float sdt[CH][16];
    __shared__ float sdx[CH][16];

    if (tid < 64) ((float4*)sB)[tid] = ((const float4*)(Bws + base * DST_))[tid];
    {
        int l = tid >> 4, j = tid & 15;        // 16x16 = 256 exactly
        sdt[l][j] = dtf[(base + l) * DI_ + dq * 16 + j];
        sdx[l][j] = dtx[(base + l) * DI_ + dq * 16 + j];
    }
    float A2 = -expf(Alog[d * DST_ + n]) * 1.44269504088896f;
    float P = 1.f, hl = 0.f;
    __syncthreads();

    #pragma unroll
    for (int l = 0; l < CH; ++l) {
        float a = exp2f(sdt[l][dl] * A2);
        P *= a;
        hl = fmaf(a, hl, sdx[l][dl] * sB[l][n]);
    }
    long o = (long)bc * 1024 + dq * 256 + tid;   // = (bc*64 + d)*16 + n
    Pst[o] = P;
    Lst[o] = hl;
}

// K4: carry combine over chunks. 2048 independent (b,d,n) chains, 48 steps.
__global__ __launch_bounds__(256) void k_scan_p2(
    const float* __restrict__ Pst, const float* __restrict__ Lst,
    float* __restrict__ Hst)
{
    const int idx = blockIdx.x * 256 + threadIdx.x;   // 0..2047
    const int b = idx >> 10, e = idx & 1023;
    float H = 0.f;
    #pragma unroll 8
    for (int c = 0; c < NCH; ++c) {
        long o = ((long)(b * NCH + c)) * 1024 + e;
        Hst[o] = H;
        H = fmaf(Pst[o], H, Lst[o]);
    }
}

// K5: fused re-scan (from true chunk-start state) + D-skip + gate + out_proj.
// 96 blocks x 1024 threads; scan over (d,n) with 16-lane shuffle reduce for y.
__global__ __launch_bounds__(1024) void k_back(
    const float* __restrict__ dtf, const float* __restrict__ dtx,
    const float* __restrict__ Bws, const float* __restrict__ Cws,
    const float* __restrict__ Alog, const float* __restrict__ Hst,
    const float* __restrict__ xs, const float* __restrict__ xz,
    const float* __restrict__ Dv, const float* __restrict__ opw,
    float* __restrict__ sp)
{
    const int bc  = blockIdx.x;
    const int b   = bc / NCH, c = bc - b * NCH;
    const int tid = threadIdx.x;
    const long base = (long)b * L_ + c * CH;   // first row of chunk

    __shared__ float sB[CH][16], sC[CH][16];
    __shared__ float sdt[CH][64], sdx[CH][64];
    __shared__ float sy[CH][65];
    __shared__ float sw[64][33];               // out_proj_w transposed, padded

    if (tid < 64) {
        ((float4*)sB)[tid] = ((const float4*)(Bws + base * DST_))[tid];
        ((float4*)sC)[tid] = ((const float4*)(Cws + base * DST_))[tid];
    }
    {
        int l = tid >> 6, dd = tid & 63;       // 16x64 = 1024 exactly
        sdt[l][dd] = dtf[(base + l) * DI_ + dd];
        sdx[l][dd] = dtx[(base + l) * DI_ + dd];
    }
    if (tid < SOUT_ * DI_) sw[tid & 63][tid >> 6] = opw[tid];

    const int d = tid >> 4, n = tid & 15;
    float A2 = -expf(Alog[d * DST_ + n]) * 1.44269504088896f;
    float h = Hst[(long)bc * 1024 + tid];
    __syncthreads();

    #pragma unroll
    for (int l = 0; l < CH; ++l) {
        float a = exp2f(sdt[l][d] * A2);
        h = fmaf(a, h, sdx[l][d] * sB[l][n]);
        float y = h * sC[l][n];
        y += __shfl_xor(y, 1);
        y += __shfl_xor(y, 2);
        y += __shfl_xor(y, 4);
        y += __shfl_xor(y, 8);
        if (n == 0) sy[l][d] = y;
    }
    __syncthreads();

    // yv = (y + xs*D) * silu(gate)
    {
        int r = tid >> 6, dd = tid & 63;
        float g  = xz[(base + r) * 128 + DI_ + dd];
        float yv = fmaf(xs[(base + r) * DI_ + dd], Dv[dd], sy[r][dd]);
        sy[r][dd] = yv * (g / (1.f + expf(-g)));
    }
    __syncthreads();

    // sp = yv @ out_proj_w.T : 16 rows x 32 outs, 64-dot each
    if (tid < CH * SOUT_) {
        int r = tid >> 5, o = tid & 31;
        float acc = 0.f;
        #pragma unroll
        for (int k = 0; k < DI_; ++k) acc = fmaf(sy[r][k], sw[k][o], acc);
        sp[(base + r) * SOUT_ + o] = acc;
    }
}

// K6: z_prime[b,s,t,f] = z[b,s,t]*zw[f] + zb[f] + sp[b,s,f]*sp[b,t,f]
__global__ __launch_bounds__(256) void k_z(
    const float* __restrict__ z, const float* __restrict__ zw,
    const float* __restrict__ zb, const float* __restrict__ sp,
    float* __restrict__ zout)
{
    const int idx = blockIdx.x * 256 + threadIdx.x;   // < B*L*L*8 = 9437184
    const int bs  = idx / 6144;         // b*L + s   (6144 = L*8 float4s)
    const int rem = idx - bs * 6144;
    const int t   = rem >> 3;
    const int f4  = rem & 7;
    const int b   = bs / L_;

    float zval = z[(long)bs * L_ + t];
    float4 w4 = ((const float4*)zw)[f4];
    float4 b4 = ((const float4*)zb)[f4];
    float4 ss = ((const float4*)sp)[bs * 8 + f4];
    float4 st = ((const float4*)sp)[(b * L_ + t) * 8 + f4];
    float4 o;
    o.x = zval * w4.x + b4.x + ss.x * st.x;
    o.y = zval * w4.y + b4.y + ss.y * st.y;
    o.z = zval * w4.z + b4.z + ss.z * st.z;
    o.w = zval * w4.w + b4.w + ss.w * st.w;
    ((float4*)zout)[(long)idx] = o;
}

extern "C" void kernel_launch(void* const* d_in, const int* in_sizes, int n_in,
                              void* d_out, int out_size, void* d_ws, size_t ws_size,
                              hipStream_t stream) {
    const float* s     = (const float*)d_in[0];
    const float* z     = (const float*)d_in[1];
    const float* spw   = (const float*)d_in[2];
    const float* spb   = (const float*)d_in[3];
    const float* zw    = (const float*)d_in[4];
    const float* zb    = (const float*)d_in[5];
    const float* ipw   = (const float*)d_in[6];
    const float* convw = (const float*)d_in[7];
    const float* convb = (const float*)d_in[8];
    const float* xpw   = (const float*)d_in[9];
    const float* dtw   = (const float*)d_in[10];
    const float* dtb   = (const float*)d_in[11];
    const float* Alog  = (const float*)d_in[12];
    const float* Dv    = (const float*)d_in[13];
    const float* opw   = (const float*)d_in[14];

    float* out = (float*)d_out;
    float* ws  = (float*)d_ws;
    float* xz  = ws;
    float* xs  = ws + 196608;
    float* dtf = ws + 294912;
    float* dtx = ws + 393216;
    float* Bws = ws + 491520;
    float* Cws = ws + 516096;
    float* Pst = ws + 540672;
    float* Lst = ws + 638976;
    float* Hst = ws + 737280;

    float* sp   = out;            // s_prime: first 49152 floats of d_out
    float* zout = out + 49152;    // z_prime: remaining 37748736 floats

    k_sproj  <<<(B_ * L_) / 4, 256, 0, stream>>>(s, spw, spb, ipw, xz);
    k_pre    <<<(B_ * L_) / 4, 256, 0, stream>>>(xz, convw, convb, xpw, dtw, dtb,
                                                 xs, dtf, dtx, Bws, Cws);
    k_scan_p1<<<B_ * NCH * 4, 256, 0, stream>>>(dtf, dtx, Bws, Alog, Pst, Lst);
    k_scan_p2<<<8, 256, 0, stream>>>(Pst, Lst, Hst);
    k_back   <<<B_ * NCH, 1024, 0, stream>>>(dtf, dtx, Bws, Cws, Alog, Hst,
                                             xs, xz, Dv, opw, sp);
    k_z      <<<(B_ * L_ * L_ * 8) / 256, 256, 0, stream>>>(z, zw, zb, sp, zout);
}

// Round 3
// 258.256 us; speedup vs baseline: 1.3627x; 1.0100x over previous
//
#include <hip/hip_runtime.h>
#include <math.h>

#define B_     2
#define L_     768
#define SIN_   1280
#define SOUT_  32
#define DI_    64
#define DST_   16
#define DCONV_ 4
#define DTR_   2
#define NCH    96      // chunks per batch (chunk = 8 rows)
#define CH     8

// ---------------- workspace layout (float offsets) ----------------
// xz   : [B*L][128]       off 0       (x = [:,0:64], gate = [:,64:128])
// xs   : [B*L][64]        off 196608
// dtf  : [B*L][64]        off 294912
// Bws  : [B*L][16]        off 393216
// Cws  : [B*L][16]        off 417792
// Pst  : [B*NCH][64][16]  off 442368   (per-chunk prod of a)
// Lst  : [B*NCH][64][16]  off 638976   (per-chunk local scan end)
// total 835584 floats = 3.34 MB (== round-2 proven footprint)

// K1: s_prime_pre = s @ s_proj_w.T + b, then xz = u @ in_proj_w.T
// 768 blocks x 256, 2 rows/block. float4 inner loop (40 iters).
__global__ __launch_bounds__(256) void k_sproj(
    const float* __restrict__ s, const float* __restrict__ spw,
    const float* __restrict__ spb, const float* __restrict__ ipw,
    float* __restrict__ xz)
{
    __shared__ float srow[2][SIN_];
    __shared__ float w2[128 * 33];          // in_proj_w, stride 33
    __shared__ float u[2][SOUT_];
    const int tid = threadIdx.x;
    const int row0 = blockIdx.x * 2;

    for (int r = 0; r < 2; ++r) {
        const float4* src = (const float4*)(s + (long)(row0 + r) * SIN_);
        for (int i = tid; i < SIN_ / 4; i += 256)
            ((float4*)srow[r])[i] = src[i];
    }
    for (int i = tid; i < 128 * 32; i += 256)
        w2[(i >> 5) * 33 + (i & 31)] = ipw[i];
    __syncthreads();

    const int f = tid >> 3;      // 0..31 output feature
    const int c = tid & 7;       // 0..7  k-slice
    float p0 = 0.f, p1 = 0.f;
    const float4* w4p = (const float4*)(spw + (long)f * SIN_);
    const float4* a0p = (const float4*)srow[0];
    const float4* a1p = (const float4*)srow[1];
    for (int k4 = c; k4 < SIN_ / 4; k4 += 8) {
        float4 w  = w4p[k4];
        float4 a0 = a0p[k4];
        float4 a1 = a1p[k4];
        p0 = fmaf(a0.x, w.x, fmaf(a0.y, w.y, fmaf(a0.z, w.z, fmaf(a0.w, w.w, p0))));
        p1 = fmaf(a1.x, w.x, fmaf(a1.y, w.y, fmaf(a1.z, w.z, fmaf(a1.w, w.w, p1))));
    }
    #pragma unroll
    for (int m = 1; m <= 4; m <<= 1) {
        p0 += __shfl_xor(p0, m);
        p1 += __shfl_xor(p1, m);
    }
    if (c == 0) {
        float bb = spb[f];
        u[0][f] = p0 + bb;
        u[1][f] = p1 + bb;
    }
    __syncthreads();

    // phase 2: 2 rows x 128 channels = 256 outputs, one per thread
    const int j = tid & 127;     // output channel of xz
    const int r = tid >> 7;      // 0..1
    float acc = 0.f;
    const float* wj = &w2[j * 33];
    #pragma unroll
    for (int k = 0; k < SOUT_; ++k) acc += u[r][k] * wj[k];
    xz[(long)(row0 + r) * 128 + j] = acc;
}

// K2: conv + SiLU + x_proj + dt path + LOCAL CHUNK SCAN (fused old p1).
// 192 blocks x 256 threads; block = one 8-row chunk.
__global__ __launch_bounds__(256) void k_pre(
    const float* __restrict__ xz, const float* __restrict__ convw,
    const float* __restrict__ convb, const float* __restrict__ xpw,
    const float* __restrict__ dtw, const float* __restrict__ dtb,
    const float* __restrict__ Alog,
    float* __restrict__ xs_out, float* __restrict__ dtf_out,
    float* __restrict__ Bws, float* __restrict__ Cws,
    float* __restrict__ Pst, float* __restrict__ Lst)
{
    const int bc = blockIdx.x;                 // b*NCH + c
    const int b  = bc / NCH, c = bc - b * NCH;
    const int l0 = c * CH;
    const long rbase = (long)b * L_ + l0;
    const int tid = threadIdx.x;

    __shared__ float sxpw[64][34];             // x_proj_w transposed
    __shared__ float sdtw[128];
    __shared__ float sxs[CH][DI_];
    __shared__ float sxd[CH][34];
    __shared__ float sdt[CH][DI_];
    __shared__ float sdx[CH][DI_];

    for (int i = tid; i < 34 * 64; i += 256)
        sxpw[i & 63][i >> 6] = xpw[i];
    if (tid < 128) sdtw[tid] = dtw[tid];

    // conv + SiLU: 8 rows x 64 d, 2 per thread
    for (int it = tid; it < CH * DI_; it += 256) {
        int r = it >> 6, d = it & 63;
        int l = l0 + r;
        float xc = convb[d];
        #pragma unroll
        for (int k = 0; k < DCONV_; ++k) {
            int ls = l + k - (DCONV_ - 1);
            if (ls >= 0) xc = fmaf(xz[(long)(b * L_ + ls) * 128 + d], convw[d * 4 + k], xc);
        }
        float xv = xc / (1.f + expf(-xc));
        sxs[r][d] = xv;
        xs_out[(rbase + r) * DI_ + d] = xv;
    }
    __syncthreads();

    // x_proj: 8 rows x 34 outs
    for (int it = tid; it < CH * 34; it += 256) {
        int r = it / 34, o = it - r * 34;
        float acc = 0.f;
        #pragma unroll
        for (int k = 0; k < DI_; ++k) acc = fmaf(sxs[r][k], sxpw[k][o], acc);
        sxd[r][o] = acc;
    }
    __syncthreads();

    // dt path (into LDS + global), B/C to global
    for (int it = tid; it < CH * DI_; it += 256) {
        int r = it >> 6, d = it & 63;
        float dtv = fmaf(sxd[r][0], sdtw[2 * d], fmaf(sxd[r][1], sdtw[2 * d + 1], dtb[d]));
        dtv = dtv > 20.f ? dtv : log1pf(expf(dtv));   // softplus
        sdt[r][d] = dtv;
        sdx[r][d] = dtv * sxs[r][d];
        dtf_out[(rbase + r) * DI_ + d] = dtv;
    }
    if (tid < CH * DST_) {                     // 128
        int r = tid >> 4, n = tid & 15;
        Bws[(rbase + r) * DST_ + n] = sxd[r][DTR_ + n];
        Cws[(rbase + r) * DST_ + n] = sxd[r][DTR_ + DST_ + n];
    }
    __syncthreads();

    // local chunk scan: (d,n) = 1024 items, 4 per thread (q over d-groups)
    const int n = tid & 15, g = tid >> 4;      // g 0..15
    float P[4], hl[4], A2[4];
    #pragma unroll
    for (int q = 0; q < 4; ++q) {
        int d = g + 16 * q;
        A2[q] = -expf(Alog[d * DST_ + n]) * 1.44269504088896f;
        P[q] = 1.f; hl[q] = 0.f;
    }
    #pragma unroll
    for (int l = 0; l < CH; ++l) {
        float bv = sxd[l][DTR_ + n];
        #pragma unroll
        for (int q = 0; q < 4; ++q) {
            int d = g + 16 * q;
            float a = exp2f(sdt[l][d] * A2[q]);
            P[q] *= a;
            hl[q] = fmaf(a, hl[q], sdx[l][d] * bv);
        }
    }
    const long o0 = (long)bc * 1024 + g * 16 + n;   // = (bc*64 + d0)*16 + n
    #pragma unroll
    for (int q = 0; q < 4; ++q) {
        Pst[o0 + 256 * q] = P[q];
        Lst[o0 + 256 * q] = hl[q];
    }
}

// K3: fused carry + re-scan + D-skip + gate + out_proj.
// 192 blocks x 1024 threads. Each block walks its own P/L prefix (<=95
// coalesced fma steps over 1024 parallel chains) to get the chunk-start
// state, then re-scans its 8 rows and runs the epilogue.
__global__ __launch_bounds__(1024) void k_back(
    const float* __restrict__ dtf, const float* __restrict__ xs,
    const float* __restrict__ Bws, const float* __restrict__ Cws,
    const float* __restrict__ Alog, const float* __restrict__ Pst,
    const float* __restrict__ Lst, const float* __restrict__ xz,
    const float* __restrict__ Dv, const float* __restrict__ opw,
    float* __restrict__ sp)
{
    const int bc = blockIdx.x;
    const int b  = bc / NCH, c = bc - b * NCH;
    const int l0 = c * CH;
    const long rbase = (long)b * L_ + l0;
    const int tid = threadIdx.x;

    __shared__ float sB[CH][DST_], sC[CH][DST_];
    __shared__ float sdt[CH][DI_], sxsS[CH][DI_];
    __shared__ float sy[CH][65];
    __shared__ float sw[64][33];               // out_proj_w transposed, padded

    if (tid < CH * DI_) {                      // 512: dt
        sdt[tid >> 6][tid & 63] = dtf[rbase * DI_ + tid];
    } else {                                   // 512: xs
        int t = tid - CH * DI_;
        sxsS[t >> 6][t & 63] = xs[rbase * DI_ + t];
    }
    if (tid < CH * DST_) {                     // 128
        sB[tid >> 4][tid & 15] = Bws[rbase * DST_ + tid];
    } else if (tid < 2 * CH * DST_) {
        int t = tid - CH * DST_;
        sC[t >> 4][t & 15] = Cws[rbase * DST_ + t];
    }
    for (int i = tid; i < SOUT_ * DI_; i += 1024)   // FIXED: full sw staged
        sw[i & 63][i >> 6] = opw[i];

    // carry: walk prefix chunks of this batch. 1024 independent chains.
    float h = 0.f;
    {
        const long ebase = (long)b * NCH * 1024 + tid;
        #pragma unroll 4
        for (int c2 = 0; c2 < c; ++c2) {
            long o = ebase + (long)c2 * 1024;
            h = fmaf(Pst[o], h, Lst[o]);
        }
    }
    const int d = tid >> 4, n = tid & 15;
    float A2 = -expf(Alog[d * DST_ + n]) * 1.44269504088896f;
    __syncthreads();

    #pragma unroll
    for (int l = 0; l < CH; ++l) {
        float dtv = sdt[l][d];
        float a = exp2f(dtv * A2);
        h = fmaf(a, h, dtv * sxsS[l][d] * sB[l][n]);
        float y = h * sC[l][n];
        y += __shfl_xor(y, 1);
        y += __shfl_xor(y, 2);
        y += __shfl_xor(y, 4);
        y += __shfl_xor(y, 8);
        if (n == 0) sy[l][d] = y;
    }
    __syncthreads();

    // yv = (y + xs*D) * silu(gate)
    if (tid < CH * DI_) {                      // 512
        int r = tid >> 6, dd = tid & 63;
        float g  = xz[(rbase + r) * 128 + DI_ + dd];
        float yv = fmaf(sxsS[r][dd], Dv[dd], sy[r][dd]);
        sy[r][dd] = yv * (g / (1.f + expf(-g)));
    }
    __syncthreads();

    // sp = yv @ out_proj_w.T : 8 rows x 32 outs, 64-dot each
    if (tid < CH * SOUT_) {                    // 256
        int r = tid >> 5, o = tid & 31;
        float acc = 0.f;
        #pragma unroll
        for (int k = 0; k < DI_; ++k) acc = fmaf(sy[r][k], sw[k][o], acc);
        sp[(rbase + r) * SOUT_ + o] = acc;
    }
}

// K4: z_prime[b,s,t,f] = z[b,s,t]*zw[f] + zb[f] + sp[b,s,f]*sp[b,t,f]
__global__ __launch_bounds__(256) void k_z(
    const float* __restrict__ z, const float* __restrict__ zw,
    const float* __restrict__ zb, const float* __restrict__ sp,
    float* __restrict__ zout)
{
    const int idx = blockIdx.x * 256 + threadIdx.x;   // < B*L*L*8 = 9437184
    const int bs  = idx / 6144;         // b*L + s   (6144 = L*8 float4s)
    const int rem = idx - bs * 6144;
    const int t   = rem >> 3;
    const int f4  = rem & 7;
    const int b   = bs / L_;

    float zval = z[(long)bs * L_ + t];
    float4 w4 = ((const float4*)zw)[f4];
    float4 b4 = ((const float4*)zb)[f4];
    float4 ss = ((const float4*)sp)[bs * 8 + f4];
    float4 st = ((const float4*)sp)[(b * L_ + t) * 8 + f4];
    float4 o;
    o.x = zval * w4.x + b4.x + ss.x * st.x;
    o.y = zval * w4.y + b4.y + ss.y * st.y;
    o.z = zval * w4.z + b4.z + ss.z * st.z;
    o.w = zval * w4.w + b4.w + ss.w * st.w;
    ((float4*)zout)[(long)idx] = o;
}

extern "C" void kernel_launch(void* const* d_in, const int* in_sizes, int n_in,
                              void* d_out, int out_size, void* d_ws, size_t ws_size,
                              hipStream_t stream) {
    const float* s     = (const float*)d_in[0];
    const float* z     = (const float*)d_in[1];
    const float* spw   = (const float*)d_in[2];
    const float* spb   = (const float*)d_in[3];
    const float* zw    = (const float*)d_in[4];
    const float* zb    = (const float*)d_in[5];
    const float* ipw   = (const float*)d_in[6];
    const float* convw = (const float*)d_in[7];
    const float* convb = (const float*)d_in[8];
    const float* xpw   = (const float*)d_in[9];
    const float* dtw   = (const float*)d_in[10];
    const float* dtb   = (const float*)d_in[11];
    const float* Alog  = (const float*)d_in[12];
    const float* Dv    = (const float*)d_in[13];
    const float* opw   = (const float*)d_in[14];

    float* out = (float*)d_out;
    float* ws  = (float*)d_ws;
    float* xz  = ws;
    float* xs  = ws + 196608;
    float* dtf = ws + 294912;
    float* Bws = ws + 393216;
    float* Cws = ws + 417792;
    float* Pst = ws + 442368;
    float* Lst = ws + 638976;

    float* sp   = out;            // s_prime: first 49152 floats of d_out
    float* zout = out + 49152;    // z_prime: remaining 37748736 floats

    k_sproj<<<(B_ * L_) / 2, 256, 0, stream>>>(s, spw, spb, ipw, xz);
    k_pre  <<<B_ * NCH, 256, 0, stream>>>(xz, convw, convb, xpw, dtw, dtb, Alog,
                                          xs, dtf, Bws, Cws, Pst, Lst);
    k_back <<<B_ * NCH, 1024, 0, stream>>>(dtf, xs, Bws, Cws, Alog, Pst, Lst,
                                           xz, Dv, opw, sp);
    k_z    <<<(B_ * L_ * L_ * 8) / 256, 256, 0, stream>>>(z, zw, zb, sp, zout);
}